// Round 4
// baseline (549.973 us; speedup 1.0000x reference)
//
#include <hip/hip_runtime.h>
#include <stdint.h>

#define NPTS 131072
#define CINC 128
#define COUTC 128
#define WDIM 512
#define K3 27
#define NTILES 1024

typedef float f32x4 __attribute__((ext_vector_type(4)));
typedef __bf16 bf16x8 __attribute__((ext_vector_type(8)));

__device__ __forceinline__ unsigned short f2bf(float x){
  union { float f; uint32_t u; } v; v.f = x;
  uint32_t u = v.u;
  uint32_t r = (u + 0x7fffu + ((u >> 16) & 1u)) >> 16;
  return (unsigned short)r;
}

// styles[b*128+c] = dot(w[b], aw[c])/sqrt(512) + ab[c]; 4 dots/block, 1/wave
__global__ void k_styles_dot(const float* __restrict__ w, const float* __restrict__ aw,
                             const float* __restrict__ ab, float* __restrict__ styles){
  int wave = threadIdx.x >> 6, lane = threadIdx.x & 63;
  int blk = blockIdx.x * 4 + wave;            // 512 dots
  int b = blk >> 7, c = blk & 127;
  const float4* wr = (const float4*)(w + b * WDIM);
  const float4* ar = (const float4*)(aw + c * WDIM);
  float4 w0 = wr[lane * 2], w1 = wr[lane * 2 + 1];
  float4 a0 = ar[lane * 2], a1 = ar[lane * 2 + 1];
  float s = w0.x * a0.x + w0.y * a0.y + w0.z * a0.z + w0.w * a0.w
          + w1.x * a1.x + w1.y * a1.y + w1.z * a1.z + w1.w * a1.w;
  for (int off = 32; off > 0; off >>= 1) s += __shfl_down(s, off, 64);
  if (lane == 0) styles[blk] = s * 0.04419417382415922f + ab[c];
}

// merged snorm + dcoefs2
__global__ void k_sn_dco(const float* __restrict__ styles, const float* __restrict__ vmat,
                         const float* __restrict__ wnorm, const float* __restrict__ mag,
                         float* __restrict__ sn, float* __restrict__ dco2){
  __shared__ float red[512];
  int t = threadIdx.x;
  float s = styles[t];
  red[t] = s * s;
  __syncthreads();
  for (int off = 256; off > 0; off >>= 1){
    if (t < off) red[t] += red[t + off];
    __syncthreads();
  }
  float rs = rsqrtf(red[0] * (1.0f / 512.0f));
  if (blockIdx.x == 0) sn[t] = s * rs;
  int wave = t >> 6, lane = t & 63;
  int pair = blockIdx.x * 8 + wave;          // b*128+co
  int b = pair >> 7, co = pair & 127;
  float s0 = styles[b * 128 + lane] * rs, s1 = styles[b * 128 + 64 + lane] * rs;
  float sum = vmat[co * 128 + lane] * s0 * s0 + vmat[co * 128 + 64 + lane] * s1 * s1;
  for (int off = 32; off > 0; off >>= 1) sum += __shfl_down(sum, off, 64);
  if (lane == 0){
    float wn = wnorm[co];
    dco2[pair] = rsqrtf(sum * wn * wn + 1e-8f) * rsqrtf(mag[0]);
  }
}

// per cout: wnorm + vmat + bpack (B-frag layout, wn-scaled)
__global__ void k_prep_w(const float* __restrict__ cw, float* __restrict__ wnorm,
                         float* __restrict__ vmat, unsigned short* __restrict__ bpack){
  __shared__ float red[128];
  int co = blockIdx.x, cin = threadIdx.x;
  const float* p = cw + co * 3456 + cin * 27;
  float r[27];
  float v = 0.f;
  #pragma unroll
  for (int k = 0; k < 27; k++){ r[k] = p[k]; v += r[k] * r[k]; }
  vmat[co * 128 + cin] = v;
  red[cin] = v;
  __syncthreads();
  for (int off = 64; off > 0; off >>= 1){
    if (cin < off) red[cin] += red[cin + off];
    __syncthreads();
  }
  float wn_s = rsqrtf(red[0] * (1.0f / 3456.0f));
  if (cin == 0) wnorm[co] = wn_s;
  int grp = co >> 4, m = co & 15;
  int kk = cin >> 5, q = (cin >> 3) & 3, j = cin & 7;
  #pragma unroll
  for (int k = 0; k < 27; k++){
    int idx = ((k * 32 + kk * 8 + grp) * 64 + q * 16 + m) * 8 + j;
    bpack[idx] = f2bf(r[k] * wn_s);
  }
}

// xpad[n][c] = bf16(x[n][c] * sn[b][c]); row NPTS = zeros
__global__ void k_xmod(const float* __restrict__ x, const float* __restrict__ sn,
                       const int* __restrict__ bidx, unsigned short* __restrict__ xpad){
  int gid = blockIdx.x * 256 + threadIdx.x;
  const int total = (NPTS + 1) * 32;
  if (gid >= total) return;
  int n = gid >> 5;
  int c4 = (gid & 31) * 4;
  unsigned short o0, o1, o2, o3;
  if (n < NPTS){
    int b = bidx[n];
    float4 xv = *(const float4*)(x + (size_t)n * CINC + c4);
    float4 sv = *(const float4*)(sn + b * CINC + c4);
    o0 = f2bf(xv.x * sv.x); o1 = f2bf(xv.y * sv.y);
    o2 = f2bf(xv.z * sv.z); o3 = f2bf(xv.w * sv.w);
  } else { o0 = o1 = o2 = o3 = 0; }
  *(ushort4*)(xpad + (size_t)n * CINC + c4) = make_ushort4(o0, o1, o2, o3);
}

// R[k][t] = lower_bound(out_idx[k], t*128), t in [0,1024]. Valid entries of
// out_idx[k] are sorted ascending with NPTS padding after, so per (tap, tile)
// contributions are the contiguous range [R[k][t], R[k][t+1]).
__global__ void k_ranges(const int* __restrict__ out_idx, int* __restrict__ R){
  int gid = blockIdx.x * 256 + threadIdx.x;       // 27*1025 = 27675
  if (gid >= K3 * (NTILES + 1)) return;
  int k = gid / (NTILES + 1), t = gid - k * (NTILES + 1);
  int target = t * 128;
  const int* lst = out_idx + k * NPTS;
  int lo = 0, hi = NPTS;
  while (lo < hi){ int mid = (lo + hi) >> 1; if (lst[mid] < target) lo = mid + 1; else hi = mid; }
  R[gid] = lo;
}

// C accumulator chunk-swizzle: float4-chunk cc of row -> chunk (cc+row)&31.
// Breaks the 512B row stride (all-rows-same-bank) while keeping 16B alignment.
__device__ __forceinline__ int caddr(int row, int col){
  return row * 128 + ((((col) >> 2) + row & 31) << 2) + (col & 3);
}

// One block = one output tile (128 rows x 128 couts), 8 waves.
// Per (tap, 16-row group) wave-task: gather A fragments straight from global
// (lane&15 = row; padding lanes read the zero row), 32 MFMA vs the tap's B,
// then ds_add_f32 the 16 result rows into the LDS C accumulator.
// Epilogue (demod+bias+leaky+clip) fused into the single coalesced store.
__global__ __launch_bounds__(512, 4) void k_out(
    const unsigned short* __restrict__ xpad,
    const unsigned short* __restrict__ bpack,
    const int* __restrict__ in_idx,
    const int* __restrict__ out_idx,
    const int* __restrict__ R,
    const float* __restrict__ dco2,
    const float* __restrict__ cbias,
    const int* __restrict__ bidx,
    float* __restrict__ out){
  __shared__ float Csh[128 * 128];   // 64KB
  int t = threadIdx.x;
  int wave = t >> 6, lane = t & 63;
  int m16 = lane & 15, q = lane >> 4;
  int tile = blockIdx.x;
  int tbase = tile * 128;

  #pragma unroll
  for (int i = 0; i < 8; i++)
    *(f32x4*)(Csh + i * 2048 + t * 4) = (f32x4){0.f, 0.f, 0.f, 0.f};
  __syncthreads();

  int tc = 0;  // global task counter (uniform across waves)
  for (int k = 0; k < K3; k++){
    int lo = R[k * (NTILES + 1) + tile];
    int hi = R[k * (NTILES + 1) + tile + 1];
    int groups = (hi - lo + 15) >> 4;
    const unsigned short* Bg = bpack + k * 16384;
    const int* ink  = in_idx  + k * NPTS;
    const int* outk = out_idx + k * NPTS;
    for (int g = 0; g < groups; g++, tc++){
      if ((tc & 7) != wave) continue;
      int e = lo + g * 16 + m16;
      int in = (e < hi) ? ink[e] : NPTS;      // NPTS -> zero row
      const unsigned short* arow = xpad + (size_t)in * CINC + q * 8;
      bf16x8 a0 = *(const bf16x8*)(arow);
      bf16x8 a1 = *(const bf16x8*)(arow + 32);
      bf16x8 a2 = *(const bf16x8*)(arow + 64);
      bf16x8 a3 = *(const bf16x8*)(arow + 96);
      f32x4 acc[8];
      #pragma unroll
      for (int j = 0; j < 8; j++) acc[j] = (f32x4){0.f, 0.f, 0.f, 0.f};
      #pragma unroll
      for (int grp = 0; grp < 8; grp++){
        bf16x8 b0 = *(const bf16x8*)(Bg + ((0 * 8 + grp) * 64 + lane) * 8);
        bf16x8 b1 = *(const bf16x8*)(Bg + ((1 * 8 + grp) * 64 + lane) * 8);
        bf16x8 b2 = *(const bf16x8*)(Bg + ((2 * 8 + grp) * 64 + lane) * 8);
        bf16x8 b3 = *(const bf16x8*)(Bg + ((3 * 8 + grp) * 64 + lane) * 8);
        acc[grp] = __builtin_amdgcn_mfma_f32_16x16x32_bf16(a0, b0, acc[grp], 0, 0, 0);
        acc[grp] = __builtin_amdgcn_mfma_f32_16x16x32_bf16(a1, b1, acc[grp], 0, 0, 0);
        acc[grp] = __builtin_amdgcn_mfma_f32_16x16x32_bf16(a2, b2, acc[grp], 0, 0, 0);
        acc[grp] = __builtin_amdgcn_mfma_f32_16x16x32_bf16(a3, b3, acc[grp], 0, 0, 0);
      }
      // scatter: C-frag row rr = q*4+r, col = grp*16+m16
      #pragma unroll
      for (int r = 0; r < 4; r++){
        int ee = lo + g * 16 + q * 4 + r;
        if (ee < hi){
          int orow = outk[ee] - tbase;        // in [0,128) by range construction
          #pragma unroll
          for (int grp = 0; grp < 8; grp++)
            unsafeAtomicAdd(&Csh[caddr(orow, grp * 16 + m16)], acc[grp][r]);
        }
      }
    }
  }
  __syncthreads();

  // fused epilogue + store: thread -> row = t>>2, col base (t&3)*32
  int row = t >> 2, cb = (t & 3) * 32;
  int n = tbase + row;
  int b = bidx[n];
  const float* dc = dco2 + b * COUTC;
  float* orow = out + (size_t)n * COUTC;
  const float S2 = 1.41421356237309515f;
  #pragma unroll
  for (int i = 0; i < 8; i++){
    int c = cb + i * 4;
    f32x4 v = *(const f32x4*)(Csh + caddr(row, c));
    float4 d = *(const float4*)(dc + c);
    float4 bi = *(const float4*)(cbias + c);
    float r0 = v.x * d.x + bi.x; r0 = (r0 < 0.f ? 0.2f * r0 : r0) * S2; r0 = fminf(fmaxf(r0, -256.f), 256.f);
    float r1 = v.y * d.y + bi.y; r1 = (r1 < 0.f ? 0.2f * r1 : r1) * S2; r1 = fminf(fmaxf(r1, -256.f), 256.f);
    float r2 = v.z * d.z + bi.z; r2 = (r2 < 0.f ? 0.2f * r2 : r2) * S2; r2 = fminf(fmaxf(r2, -256.f), 256.f);
    float r3 = v.w * d.w + bi.w; r3 = (r3 < 0.f ? 0.2f * r3 : r3) * S2; r3 = fminf(fmaxf(r3, -256.f), 256.f);
    *(float4*)(orow + c) = make_float4(r0, r1, r2, r3);
  }
}

extern "C" void kernel_launch(void* const* d_in, const int* in_sizes, int n_in,
                              void* d_out, int out_size, void* d_ws, size_t ws_size,
                              hipStream_t stream){
  const float* x   = (const float*)d_in[0];
  const float* w   = (const float*)d_in[1];
  const float* aw  = (const float*)d_in[2];
  const float* ab  = (const float*)d_in[3];
  const float* cw  = (const float*)d_in[4];
  const float* cb  = (const float*)d_in[5];
  const float* mag = (const float*)d_in[6];
  const int* bidx    = (const int*)d_in[7];
  const int* in_idx  = (const int*)d_in[8];
  const int* out_idx = (const int*)d_in[9];
  float* out = (float*)d_out;
  char* ws = (char*)d_ws;

  float* styles = (float*)(ws + 0);         // 2048 B
  float* sn     = (float*)(ws + 2048);      // 2048 B
  float* wnorm  = (float*)(ws + 4096);      // 512 B
  float* dco2   = (float*)(ws + 4608);      // 2048 B
  float* vmat   = (float*)(ws + 8192);      // 65536 B
  unsigned short* bpack = (unsigned short*)(ws + 73728);    // 884736 B
  unsigned short* xpad  = (unsigned short*)(ws + 958464);   // 33554688 B
  int* R        = (int*)(ws + 34513152);                    // 110700 B -> end 34623852

  k_prep_w<<<128, 128, 0, stream>>>(cw, wnorm, vmat, bpack);
  k_styles_dot<<<128, 256, 0, stream>>>(w, aw, ab, styles);
  k_sn_dco<<<64, 512, 0, stream>>>(styles, vmat, wnorm, mag, sn, dco2);
  k_xmod<<<16385, 256, 0, stream>>>(x, sn, bidx, xpad);
  k_ranges<<<109, 256, 0, stream>>>(out_idx, R);
  k_out<<<NTILES, 512, 0, stream>>>(xpad, bpack, in_idx, out_idx, R, dco2, cb, bidx, out);
}

// Round 5
// 549.112 us; speedup vs baseline: 1.0016x; 1.0016x over previous
//
#include <hip/hip_runtime.h>
#include <stdint.h>

#define NPTS 131072
#define CINC 128
#define COUTC 128
#define WDIM 512
#define K3 27
#define NTILES 1024

typedef float f32x4 __attribute__((ext_vector_type(4)));
typedef __bf16 bf16x8 __attribute__((ext_vector_type(8)));

__device__ __forceinline__ unsigned short f2bf(float x){
  union { float f; uint32_t u; } v; v.f = x;
  uint32_t u = v.u;
  uint32_t r = (u + 0x7fffu + ((u >> 16) & 1u)) >> 16;
  return (unsigned short)r;
}

// styles[b*128+c] = dot(w[b], aw[c])/sqrt(512) + ab[c]; 4 dots/block, 1/wave
__global__ void k_styles_dot(const float* __restrict__ w, const float* __restrict__ aw,
                             const float* __restrict__ ab, float* __restrict__ styles){
  int wave = threadIdx.x >> 6, lane = threadIdx.x & 63;
  int blk = blockIdx.x * 4 + wave;            // 512 dots
  int b = blk >> 7, c = blk & 127;
  const float4* wr = (const float4*)(w + b * WDIM);
  const float4* ar = (const float4*)(aw + c * WDIM);
  float4 w0 = wr[lane * 2], w1 = wr[lane * 2 + 1];
  float4 a0 = ar[lane * 2], a1 = ar[lane * 2 + 1];
  float s = w0.x * a0.x + w0.y * a0.y + w0.z * a0.z + w0.w * a0.w
          + w1.x * a1.x + w1.y * a1.y + w1.z * a1.z + w1.w * a1.w;
  for (int off = 32; off > 0; off >>= 1) s += __shfl_down(s, off, 64);
  if (lane == 0) styles[blk] = s * 0.04419417382415922f + ab[c];
}

// merged snorm + dcoefs2
__global__ void k_sn_dco(const float* __restrict__ styles, const float* __restrict__ vmat,
                         const float* __restrict__ wnorm, const float* __restrict__ mag,
                         float* __restrict__ sn, float* __restrict__ dco2){
  __shared__ float red[512];
  int t = threadIdx.x;
  float s = styles[t];
  red[t] = s * s;
  __syncthreads();
  for (int off = 256; off > 0; off >>= 1){
    if (t < off) red[t] += red[t + off];
    __syncthreads();
  }
  float rs = rsqrtf(red[0] * (1.0f / 512.0f));
  if (blockIdx.x == 0) sn[t] = s * rs;
  int wave = t >> 6, lane = t & 63;
  int pair = blockIdx.x * 8 + wave;          // b*128+co
  int b = pair >> 7, co = pair & 127;
  float s0 = styles[b * 128 + lane] * rs, s1 = styles[b * 128 + 64 + lane] * rs;
  float sum = vmat[co * 128 + lane] * s0 * s0 + vmat[co * 128 + 64 + lane] * s1 * s1;
  for (int off = 32; off > 0; off >>= 1) sum += __shfl_down(sum, off, 64);
  if (lane == 0){
    float wn = wnorm[co];
    dco2[pair] = rsqrtf(sum * wn * wn + 1e-8f) * rsqrtf(mag[0]);
  }
}

// per cout: wnorm + vmat + bpack (B-frag layout, wn-scaled)
__global__ void k_prep_w(const float* __restrict__ cw, float* __restrict__ wnorm,
                         float* __restrict__ vmat, unsigned short* __restrict__ bpack){
  __shared__ float red[128];
  int co = blockIdx.x, cin = threadIdx.x;
  const float* p = cw + co * 3456 + cin * 27;
  float r[27];
  float v = 0.f;
  #pragma unroll
  for (int k = 0; k < 27; k++){ r[k] = p[k]; v += r[k] * r[k]; }
  vmat[co * 128 + cin] = v;
  red[cin] = v;
  __syncthreads();
  for (int off = 64; off > 0; off >>= 1){
    if (cin < off) red[cin] += red[cin + off];
    __syncthreads();
  }
  float wn_s = rsqrtf(red[0] * (1.0f / 3456.0f));
  if (cin == 0) wnorm[co] = wn_s;
  int grp = co >> 4, m = co & 15;
  int kk = cin >> 5, q = (cin >> 3) & 3, j = cin & 7;
  #pragma unroll
  for (int k = 0; k < 27; k++){
    int idx = ((k * 32 + kk * 8 + grp) * 64 + q * 16 + m) * 8 + j;
    bpack[idx] = f2bf(r[k] * wn_s);
  }
}

// xpad[n][c] = bf16(x[n][c] * sn[b][c]); row NPTS = zeros
__global__ void k_xmod(const float* __restrict__ x, const float* __restrict__ sn,
                       const int* __restrict__ bidx, unsigned short* __restrict__ xpad){
  int gid = blockIdx.x * 256 + threadIdx.x;
  const int total = (NPTS + 1) * 32;
  if (gid >= total) return;
  int n = gid >> 5;
  int c4 = (gid & 31) * 4;
  unsigned short o0, o1, o2, o3;
  if (n < NPTS){
    int b = bidx[n];
    float4 xv = *(const float4*)(x + (size_t)n * CINC + c4);
    float4 sv = *(const float4*)(sn + b * CINC + c4);
    o0 = f2bf(xv.x * sv.x); o1 = f2bf(xv.y * sv.y);
    o2 = f2bf(xv.z * sv.z); o3 = f2bf(xv.w * sv.w);
  } else { o0 = o1 = o2 = o3 = 0; }
  *(ushort4*)(xpad + (size_t)n * CINC + c4) = make_ushort4(o0, o1, o2, o3);
}

// R[k][t] = lower_bound(out_idx[k], t*128); per (tap,tile) range = [R[k][t],R[k][t+1])
__global__ void k_ranges(const int* __restrict__ out_idx, int* __restrict__ R){
  int gid = blockIdx.x * 256 + threadIdx.x;       // 27*1025 = 27675
  if (gid >= K3 * (NTILES + 1)) return;
  int k = gid / (NTILES + 1), t = gid - k * (NTILES + 1);
  int target = t * 128;
  const int* lst = out_idx + k * NPTS;
  int lo = 0, hi = NPTS;
  while (lo < hi){ int mid = (lo + hi) >> 1; if (lst[mid] < target) lo = mid + 1; else hi = mid; }
  R[gid] = lo;
}

// C accumulator chunk-swizzle: float4-chunk cc of row -> chunk (cc+row)&31
__device__ __forceinline__ int caddr(int row, int col){
  return row * 128 + ((((col >> 2) + row) & 31) << 2) + (col & 3);
}

// One block = one output tile (128 rows x 128 couts), 8 waves.
// Wave-register task table (27-lane lo/hi + prefix scan, ballot/shfl decode),
// 2-deep pipelined tasks, inline-asm ds_add_f32 scatter into LDS C,
// fused demod/bias/leaky/clip epilogue.
__global__ __launch_bounds__(512, 4) void k_out(
    const unsigned short* __restrict__ xpad,
    const unsigned short* __restrict__ bpack,
    const int* __restrict__ in_idx,
    const int* __restrict__ out_idx,
    const int* __restrict__ R,
    const float* __restrict__ dco2,
    const float* __restrict__ cbias,
    const int* __restrict__ bidx,
    float* __restrict__ out){
  __shared__ float Csh[128 * 128];   // 64KB
  int t = threadIdx.x;
  int wave = t >> 6, lane = t & 63;
  int m16 = lane & 15, q = lane >> 4;
  int tile = blockIdx.x;
  int tbase = tile * 128;

  #pragma unroll
  for (int i = 0; i < 8; i++)
    *(f32x4*)(Csh + i * 2048 + t * 4) = (f32x4){0.f, 0.f, 0.f, 0.f};

  // ---- per-wave task table in registers: lane k<27 holds tap k's lo/hi/base
  int lo = 0, hi = 0, grps = 0;
  if (lane < 27){
    lo = R[lane * (NTILES + 1) + tile];
    hi = R[lane * (NTILES + 1) + tile + 1];
    grps = (hi - lo + 15) >> 4;
  }
  int scan = grps;
  #pragma unroll
  for (int off = 1; off < 32; off <<= 1){
    int v = __shfl_up(scan, off, 64);
    if (lane >= off) scan += v;
  }
  int base = scan - grps;                 // exclusive prefix
  int T = __shfl(scan, 26, 64);           // total tasks (>= 8: center tap)

  __syncthreads();                        // C zeroed before any ds_add

  // decode task tt -> (tap k, estart, hi_k); uniform per wave
  auto decode = [&](int tt, int& k_, int& es_, int& hi_){
    unsigned long long mask = __ballot((lane < 27) && (base <= tt));
    int k = __popcll(mask) - 1;
    int b0 = __shfl(base, k, 64);
    int l0 = __shfl(lo, k, 64);
    hi_ = __shfl(hi, k, 64);
    k_ = k;
    es_ = l0 + (tt - b0) * 16;
  };

  // stage task tt: index gathers (in_idx row for lane m16; out rows for q*4+r)
  auto stage = [&](int tt, int& k_, int& es_, int& hi_, int& inv_, int* oi_){
    if (tt < T){
      decode(tt, k_, es_, hi_);
      int e = es_ + m16;
      inv_ = (e < hi_) ? in_idx[k_ * NPTS + e] : NPTS;
      #pragma unroll
      for (int r = 0; r < 4; r++){
        int ee = es_ + q * 4 + r;
        oi_[r] = (ee < hi_) ? out_idx[k_ * NPTS + ee] : -1;
      }
    } else {
      k_ = 0; es_ = 0; hi_ = -1; inv_ = NPTS;
      #pragma unroll
      for (int r = 0; r < 4; r++) oi_[r] = -1;
    }
  };

  // ---- 2-deep pipeline
  int k1, es1, hi1, inv1, oi1[4];
  int k2, es2, hi2, inv2, oi2[4];
  stage(wave, k1, es1, hi1, inv1, oi1);
  const unsigned short* ar1 = xpad + (size_t)inv1 * CINC + q * 8;
  bf16x8 a0 = *(const bf16x8*)(ar1);
  bf16x8 a1 = *(const bf16x8*)(ar1 + 32);
  bf16x8 a2 = *(const bf16x8*)(ar1 + 64);
  bf16x8 a3 = *(const bf16x8*)(ar1 + 96);
  stage(wave + 8, k2, es2, hi2, inv2, oi2);

  for (int tt = wave; tt < T; tt += 8){
    // issue next task's A gather (hidden under current MFMAs)
    const unsigned short* ar2 = xpad + (size_t)inv2 * CINC + q * 8;
    bf16x8 n0 = *(const bf16x8*)(ar2);
    bf16x8 n1 = *(const bf16x8*)(ar2 + 32);
    bf16x8 n2 = *(const bf16x8*)(ar2 + 64);
    bf16x8 n3 = *(const bf16x8*)(ar2 + 96);

    // stage task tt+16 (indices in flight under MFMAs)
    int k3, es3, hi3, inv3, oi3[4];
    stage(tt + 16, k3, es3, hi3, inv3, oi3);

    // MFMA: 16 rows x 128 couts x K=128 for tap k1
    const unsigned short* Bg = bpack + k1 * 16384;
    f32x4 acc[8];
    #pragma unroll
    for (int j = 0; j < 8; j++) acc[j] = (f32x4){0.f, 0.f, 0.f, 0.f};
    #pragma unroll
    for (int grp = 0; grp < 8; grp++){
      bf16x8 b0 = *(const bf16x8*)(Bg + ((0 * 8 + grp) * 64 + lane) * 8);
      bf16x8 b1 = *(const bf16x8*)(Bg + ((1 * 8 + grp) * 64 + lane) * 8);
      bf16x8 b2 = *(const bf16x8*)(Bg + ((2 * 8 + grp) * 64 + lane) * 8);
      bf16x8 b3 = *(const bf16x8*)(Bg + ((3 * 8 + grp) * 64 + lane) * 8);
      acc[grp] = __builtin_amdgcn_mfma_f32_16x16x32_bf16(a0, b0, acc[grp], 0, 0, 0);
      acc[grp] = __builtin_amdgcn_mfma_f32_16x16x32_bf16(a1, b1, acc[grp], 0, 0, 0);
      acc[grp] = __builtin_amdgcn_mfma_f32_16x16x32_bf16(a2, b2, acc[grp], 0, 0, 0);
      acc[grp] = __builtin_amdgcn_mfma_f32_16x16x32_bf16(a3, b3, acc[grp], 0, 0, 0);
    }

    // scatter-add into LDS C: guaranteed HW ds_add_f32 via inline asm
    #pragma unroll
    for (int r = 0; r < 4; r++){
      if (oi1[r] >= 0){
        int orow = oi1[r] - tbase;          // in [0,128) by range construction
        #pragma unroll
        for (int grp = 0; grp < 8; grp++){
          uint32_t ad = (uint32_t)(size_t)&Csh[caddr(orow, grp * 16 + m16)];
          float vv = acc[grp][r];
          asm volatile("ds_add_f32 %0, %1" :: "v"(ad), "v"(vv) : "memory");
        }
      }
    }

    // rotate pipeline
    k1 = k2; es1 = es2; hi1 = hi2; inv1 = inv2;
    #pragma unroll
    for (int r = 0; r < 4; r++) oi1[r] = oi2[r];
    a0 = n0; a1 = n1; a2 = n2; a3 = n3;
    k2 = k3; es2 = es3; hi2 = hi3; inv2 = inv3;
    #pragma unroll
    for (int r = 0; r < 4; r++) oi2[r] = oi3[r];
  }

  __syncthreads();   // drains lgkm (ds_add) + barrier

  // fused epilogue + store: thread -> row = t>>2, col base (t&3)*32
  int row = t >> 2, cb = (t & 3) * 32;
  int n = tbase + row;
  int b = bidx[n];
  const float* dc = dco2 + b * COUTC;
  float* orow = out + (size_t)n * COUTC;
  const float S2 = 1.41421356237309515f;
  #pragma unroll
  for (int i = 0; i < 8; i++){
    int c = cb + i * 4;
    f32x4 v = *(const f32x4*)(Csh + caddr(row, c));
    float4 d = *(const float4*)(dc + c);
    float4 bi = *(const float4*)(cbias + c);
    float r0 = v.x * d.x + bi.x; r0 = (r0 < 0.f ? 0.2f * r0 : r0) * S2; r0 = fminf(fmaxf(r0, -256.f), 256.f);
    float r1 = v.y * d.y + bi.y; r1 = (r1 < 0.f ? 0.2f * r1 : r1) * S2; r1 = fminf(fmaxf(r1, -256.f), 256.f);
    float r2 = v.z * d.z + bi.z; r2 = (r2 < 0.f ? 0.2f * r2 : r2) * S2; r2 = fminf(fmaxf(r2, -256.f), 256.f);
    float r3 = v.w * d.w + bi.w; r3 = (r3 < 0.f ? 0.2f * r3 : r3) * S2; r3 = fminf(fmaxf(r3, -256.f), 256.f);
    *(float4*)(orow + c) = make_float4(r0, r1, r2, r3);
  }
}

extern "C" void kernel_launch(void* const* d_in, const int* in_sizes, int n_in,
                              void* d_out, int out_size, void* d_ws, size_t ws_size,
                              hipStream_t stream){
  const float* x   = (const float*)d_in[0];
  const float* w   = (const float*)d_in[1];
  const float* aw  = (const float*)d_in[2];
  const float* ab  = (const float*)d_in[3];
  const float* cw  = (const float*)d_in[4];
  const float* cb  = (const float*)d_in[5];
  const float* mag = (const float*)d_in[6];
  const int* bidx    = (const int*)d_in[7];
  const int* in_idx  = (const int*)d_in[8];
  const int* out_idx = (const int*)d_in[9];
  float* out = (float*)d_out;
  char* ws = (char*)d_ws;

  float* styles = (float*)(ws + 0);         // 2048 B
  float* sn     = (float*)(ws + 2048);      // 2048 B
  float* wnorm  = (float*)(ws + 4096);      // 512 B
  float* dco2   = (float*)(ws + 4608);      // 2048 B
  float* vmat   = (float*)(ws + 8192);      // 65536 B
  unsigned short* bpack = (unsigned short*)(ws + 73728);    // 884736 B
  unsigned short* xpad  = (unsigned short*)(ws + 958464);   // 33554688 B
  int* R        = (int*)(ws + 34513152);                    // 110700 B -> end 34623852

  k_prep_w<<<128, 128, 0, stream>>>(cw, wnorm, vmat, bpack);
  k_styles_dot<<<128, 256, 0, stream>>>(w, aw, ab, styles);
  k_sn_dco<<<64, 512, 0, stream>>>(styles, vmat, wnorm, mag, sn, dco2);
  k_xmod<<<16385, 256, 0, stream>>>(x, sn, bidx, xpad);
  k_ranges<<<109, 256, 0, stream>>>(out_idx, R);
  k_out<<<NTILES, 512, 0, stream>>>(xpad, bpack, in_idx, out_idx, R, dco2, cb, bidx, out);
}

// Round 8
// 322.019 us; speedup vs baseline: 1.7079x; 1.7052x over previous
//
#include <hip/hip_runtime.h>
#include <stdint.h>

#define NPTS 131072
#define CINC 128
#define COUTC 128
#define WDIM 512
#define K3 27

typedef float f32x4 __attribute__((ext_vector_type(4)));
typedef __bf16 bf16x8 __attribute__((ext_vector_type(8)));

#define GLOAD_LDS16(g, l) \
  __builtin_amdgcn_global_load_lds((const __attribute__((address_space(1))) void*)(g), \
                                   (__attribute__((address_space(3))) void*)(l), 16, 0, 0)

__device__ __forceinline__ unsigned short f2bf(float x){
  union { float f; uint32_t u; } v; v.f = x;
  uint32_t u = v.u;
  uint32_t r = (u + 0x7fffu + ((u >> 16) & 1u)) >> 16;
  return (unsigned short)r;
}

// styles[b*128+c] = dot(w[b], aw[c])/sqrt(512) + ab[c]; 4 dots/block, 1/wave
__global__ void k_styles_dot(const float* __restrict__ w, const float* __restrict__ aw,
                             const float* __restrict__ ab, float* __restrict__ styles){
  int wave = threadIdx.x >> 6, lane = threadIdx.x & 63;
  int blk = blockIdx.x * 4 + wave;            // 512 dots
  int b = blk >> 7, c = blk & 127;
  const float4* wr = (const float4*)(w + b * WDIM);
  const float4* ar = (const float4*)(aw + c * WDIM);
  float4 w0 = wr[lane * 2], w1 = wr[lane * 2 + 1];
  float4 a0 = ar[lane * 2], a1 = ar[lane * 2 + 1];
  float s = w0.x * a0.x + w0.y * a0.y + w0.z * a0.z + w0.w * a0.w
          + w1.x * a1.x + w1.y * a1.y + w1.z * a1.z + w1.w * a1.w;
  for (int off = 32; off > 0; off >>= 1) s += __shfl_down(s, off, 64);
  if (lane == 0) styles[blk] = s * 0.04419417382415922f + ab[c];
}

// merged snorm + dcoefs2: every block redundantly reduces styles^2 (2KB), then
// wave w computes dco2 for pair = blk*8+w; block 0 additionally writes sn[].
__global__ void k_sn_dco(const float* __restrict__ styles, const float* __restrict__ vmat,
                         const float* __restrict__ wnorm, const float* __restrict__ mag,
                         float* __restrict__ sn, float* __restrict__ dco2){
  __shared__ float red[512];
  int t = threadIdx.x;
  float s = styles[t];
  red[t] = s * s;
  __syncthreads();
  for (int off = 256; off > 0; off >>= 1){
    if (t < off) red[t] += red[t + off];
    __syncthreads();
  }
  float rs = rsqrtf(red[0] * (1.0f / 512.0f));
  if (blockIdx.x == 0) sn[t] = s * rs;
  int wave = t >> 6, lane = t & 63;
  int pair = blockIdx.x * 8 + wave;          // b*128+co
  int b = pair >> 7, co = pair & 127;
  float s0 = styles[b * 128 + lane] * rs, s1 = styles[b * 128 + 64 + lane] * rs;
  float sum = vmat[co * 128 + lane] * s0 * s0 + vmat[co * 128 + 64 + lane] * s1 * s1;
  for (int off = 32; off > 0; off >>= 1) sum += __shfl_down(sum, off, 64);
  if (lane == 0){
    float wn = wnorm[co];
    dco2[pair] = rsqrtf(sum * wn * wn + 1e-8f) * rsqrtf(mag[0]);
  }
}

// per cout: wnorm + vmat[cout][cin]=sum_k cw^2 + bpack (B-frag layout, wn-scaled)
__global__ void k_prep_w(const float* __restrict__ cw, float* __restrict__ wnorm,
                         float* __restrict__ vmat, unsigned short* __restrict__ bpack){
  __shared__ float red[128];
  int co = blockIdx.x, cin = threadIdx.x;
  const float* p = cw + co * 3456 + cin * 27;
  float r[27];
  float v = 0.f;
  #pragma unroll
  for (int k = 0; k < 27; k++){ r[k] = p[k]; v += r[k] * r[k]; }
  vmat[co * 128 + cin] = v;
  red[cin] = v;
  __syncthreads();
  for (int off = 64; off > 0; off >>= 1){
    if (cin < off) red[cin] += red[cin + off];
    __syncthreads();
  }
  float wn_s = rsqrtf(red[0] * (1.0f / 3456.0f));
  if (cin == 0) wnorm[co] = wn_s;
  int grp = co >> 4, m = co & 15;
  int kk = cin >> 5, q = (cin >> 3) & 3, j = cin & 7;
  #pragma unroll
  for (int k = 0; k < 27; k++){
    int idx = ((k * 32 + kk * 8 + grp) * 64 + q * 16 + m) * 8 + j;
    bpack[idx] = f2bf(r[k] * wn_s);
  }
}

// xpad[n][c] = bf16(x[n][c] * sn[b][c]); row NPTS = zeros
__global__ void k_xmod(const float* __restrict__ x, const float* __restrict__ sn,
                       const int* __restrict__ bidx, unsigned short* __restrict__ xpad){
  int gid = blockIdx.x * 256 + threadIdx.x;
  const int total = (NPTS + 1) * 32;
  if (gid >= total) return;
  int n = gid >> 5;
  int c4 = (gid & 31) * 4;
  unsigned short o0, o1, o2, o3;
  if (n < NPTS){
    int b = bidx[n];
    float4 xv = *(const float4*)(x + (size_t)n * CINC + c4);
    float4 sv = *(const float4*)(sn + b * CINC + c4);
    o0 = f2bf(xv.x * sv.x); o1 = f2bf(xv.y * sv.y);
    o2 = f2bf(xv.z * sv.z); o3 = f2bf(xv.w * sv.w);
  } else { o0 = o1 = o2 = o3 = 0; }
  *(ushort4*)(xpad + (size_t)n * CINC + c4) = make_ushort4(o0, o1, o2, o3);
}

__global__ void k_invinit(int* __restrict__ invT){
  int j = blockIdx.x * 256 + threadIdx.x;
  int k = blockIdx.y;
  invT[k * NPTS + j] = NPTS;
}

__global__ void k_invscat(const int* __restrict__ out_idx, const int* __restrict__ in_idx,
                          int* __restrict__ invT){
  int j = blockIdx.x * 256 + threadIdx.x;
  int k = blockIdx.y;
  int o = out_idx[k * NPTS + j];
  if (o < NPTS) invT[k * NPTS + o] = in_idx[k * NPTS + j];
}

// Main conv: block = 64 output points x 128 couts, 4 waves (2M x 2N), 256 thr.
// Same verified structure as the 128-tile version (R0, 169us), retiled so the
// LDS A double-buffer is 2x16KB = 32KB -> 4 resident blocks/CU (was 2).
// Theory: the wall is gather L2-miss concurrency (xpad is 33MB random -> L3);
// 2x more resident blocks = 2x more independent gather streams in flight.
// NOTE: launch_bounds min-waves 4 (not 5): 5x32KB = exactly 160KB LDS was the
// only novel property of the twice-failed R6 config; 4x32KB = 128KB keeps
// the same pool headroom ratio as the known-good 512-thread/64KB version.
__global__ __launch_bounds__(256, 4) void k_conv(
    const unsigned short* __restrict__ xpad,
    const unsigned short* __restrict__ bpack,
    const int* __restrict__ invT,
    const float* __restrict__ dco2,
    const float* __restrict__ cbias,
    const int* __restrict__ bidx,
    float* __restrict__ out){
  __shared__ __align__(16) unsigned short Ash[2 * 64 * 128];  // 32KB double buffer
  int t = threadIdx.x;
  int wave = t >> 6, lane = t & 63;
  int wm = wave >> 1, wn = wave & 1;
  int q = lane >> 4, m16 = lane & 15;
  int base_pt = blockIdx.x * 64;

  f32x4 acc[2][4];
  #pragma unroll
  for (int i = 0; i < 2; i++)
    #pragma unroll
    for (int j = 0; j < 4; j++) acc[i][j] = (f32x4){0.f, 0.f, 0.f, 0.f};

  // prefetch tap k into buffer bufsel: source-lane XOR swizzle keeps LDS dest lane-linear
  auto prefetch = [&](int k, int bufsel){
    const int* invk = invT + k * NPTS + base_pt;
    unsigned short* Ab = Ash + bufsel * (64 * 128);
    #pragma unroll
    for (int i = 0; i < 4; i++){
      int chunk = i * 256 + t;              // 1024 chunks = 64 rows x 16
      int row = chunk >> 4, c = chunk & 15;
      int inv = invk[row];
      const unsigned short* src = xpad + (size_t)inv * CINC + ((c ^ row) & 15) * 8;
      GLOAD_LDS16(src, Ab + chunk * 8);
    }
  };

  prefetch(0, 0);
  for (int k = 0; k < K3; k++){
    __syncthreads();                      // drains prefetch(k); releases buf[(k+1)&1]
    if (k + 1 < K3) prefetch(k + 1, (k + 1) & 1);
    const unsigned short* Ab = Ash + (k & 1) * (64 * 128);
    const unsigned short* Bg = bpack + k * 16384;
    #pragma unroll
    for (int kk = 0; kk < 4; kk++){
      int cA = ((kk * 4 + q) ^ m16) & 15;
      bf16x8 a0 = *(const bf16x8*)(Ab + (wm * 32 + m16) * 128 + cA * 8);
      bf16x8 a1 = *(const bf16x8*)(Ab + (wm * 32 + 16 + m16) * 128 + cA * 8);
      #pragma unroll
      for (int jn = 0; jn < 4; jn++){
        bf16x8 b = *(const bf16x8*)(Bg + ((kk * 8 + wn * 4 + jn) * 64 + lane) * 8);
        acc[0][jn] = __builtin_amdgcn_mfma_f32_16x16x32_bf16(a0, b, acc[0][jn], 0, 0, 0);
        acc[1][jn] = __builtin_amdgcn_mfma_f32_16x16x32_bf16(a1, b, acc[1][jn], 0, 0, 0);
      }
    }
  }

  // epilogue: demod + bias + leaky*sqrt2 + clip
  const float S2 = 1.41421356237309515f;
  #pragma unroll
  for (int i = 0; i < 2; i++){
    #pragma unroll
    for (int r = 0; r < 4; r++){
      int row = wm * 32 + i * 16 + q * 4 + r;   // D: row=(lane>>4)*4+reg
      int n = base_pt + row;
      int b = bidx[n];
      const float* dc = dco2 + b * COUTC;
      float* orow = out + (size_t)n * COUTC;
      #pragma unroll
      for (int jn = 0; jn < 4; jn++){
        int col = wn * 64 + jn * 16 + m16;      // D: col=lane&15
        float v = acc[i][jn][r] * dc[col] + cbias[col];
        v = (v < 0.f ? 0.2f * v : v) * S2;
        v = fminf(fmaxf(v, -256.f), 256.f);
        orow[col] = v;
      }
    }
  }
}

extern "C" void kernel_launch(void* const* d_in, const int* in_sizes, int n_in,
                              void* d_out, int out_size, void* d_ws, size_t ws_size,
                              hipStream_t stream){
  const float* x   = (const float*)d_in[0];
  const float* w   = (const float*)d_in[1];
  const float* aw  = (const float*)d_in[2];
  const float* ab  = (const float*)d_in[3];
  const float* cw  = (const float*)d_in[4];
  const float* cb  = (const float*)d_in[5];
  const float* mag = (const float*)d_in[6];
  const int* bidx    = (const int*)d_in[7];
  const int* in_idx  = (const int*)d_in[8];
  const int* out_idx = (const int*)d_in[9];
  float* out = (float*)d_out;
  char* ws = (char*)d_ws;

  float* styles = (float*)(ws + 0);         // 2048 B
  float* sn     = (float*)(ws + 2048);      // 2048 B
  float* wnorm  = (float*)(ws + 4096);      // 512 B
  float* dco2   = (float*)(ws + 4608);      // 2048 B
  float* vmat   = (float*)(ws + 8192);      // 65536 B
  unsigned short* bpack = (unsigned short*)(ws + 73728);    // 884736 B
  unsigned short* xpad  = (unsigned short*)(ws + 958464);   // 33554688 B
  int* invT     = (int*)(ws + 34513152);                    // 14155776 B -> end 48668928

  k_prep_w<<<128, 128, 0, stream>>>(cw, wnorm, vmat, bpack);
  k_styles_dot<<<128, 256, 0, stream>>>(w, aw, ab, styles);
  k_sn_dco<<<64, 512, 0, stream>>>(styles, vmat, wnorm, mag, sn, dco2);
  k_xmod<<<16385, 256, 0, stream>>>(x, sn, bidx, xpad);
  dim3 gi(512, 27);
  k_invinit<<<gi, 256, 0, stream>>>(invT);
  k_invscat<<<gi, 256, 0, stream>>>(out_idx, in_idx, invT);
  k_conv<<<2048, 256, 0, stream>>>(xpad, bpack, invT, dco2, cb, bidx, out);
}